// Round 5
// baseline (288.119 us; speedup 1.0000x reference)
//
#include <hip/hip_runtime.h>
#include <cstddef>

// Problem constants (match reference)
constexpr int Bn  = 2048;
constexpr int Dn  = 512;
constexpr int CAP = 262144;   // candidate key capacity (expected ~41K worst bucket)

// VERIFIED INVARIANT (R4): reference adc[i][j] = fl32( single fma chain k=0..511 ) / 0.07f,
// strict ascending k, one fused fma per step, single accumulator. DO NOT reassociate,
// split K, or use MFMA — masks flip at sub-ulp rank gaps.

// ---------------- workspace control block ----------------
struct Ctl {
  unsigned hist1[4096];
  unsigned hist2[4096];
  unsigned k;
  int      b1;
  unsigned above1;
  unsigned candCount;
  float    thrF;
  unsigned singles;
  double   lossSum;
  unsigned cand[CAP];   // exact fp32 keys of candidates in bucket b1
};

// Monotone fp32 <-> uint32 order keys
__device__ inline unsigned key_of(float L) {
  unsigned u = __float_as_uint(L);
  return (u & 0x80000000u) ? ~u : (u | 0x80000000u);
}
__device__ inline float key_to_float(unsigned key) {
  unsigned u = (key & 0x80000000u) ? (key ^ 0x80000000u) : ~key;
  return __uint_as_float(u);
}

// Deterministic monotone bucketing (identical expressions in every kernel).
// Pass 1: linear [-64,0), width 1/64; pass 2: refine b1 by 4096 (width 2^-18).
__device__ inline int idx1_of(float v) {
  float x = (v + 64.0f) * 64.0f;       // add-then-mul: not contractible
  int i = (int)x;
  return i < 0 ? 0 : (i > 4095 ? 4095 : i);
}
__device__ inline int idx2_of(float v, float lo1) {
  float x = (v - lo1) * 262144.0f;
  int i = (int)x;
  return i < 0 ? 0 : (i > 4095 ? 4095 : i);
}

// ---------------- GEMM: 128x128 tile, 8x8 microtile, dbuf LDS, fused row-max ----------------
__global__ __launch_bounds__(256) void gemm_adc(const float* __restrict__ F,
                                                float* __restrict__ adc,
                                                unsigned* __restrict__ rowKey) {
  __shared__ float As[2][16][132];
  __shared__ float Bs[2][16][132];
  __shared__ unsigned rmax[128];
  const int t    = threadIdx.x;
  const int tx   = t & 15, ty = t >> 4;
  const int lrow = t & 127, lq = t >> 7;          // loader: row 0..127, quad-sel 0..1
  const int i0   = blockIdx.y * 128, j0 = blockIdx.x * 128;

  float acc[8][8] = {};

  const float* Abase = F + (size_t)(i0 + lrow) * Dn;
  const float* Bbase = F + (size_t)(j0 + lrow) * Dn;

  // prologue: stage chunk 0
  float4 a0 = *(const float4*)(Abase + lq * 4);
  float4 a1 = *(const float4*)(Abase + (lq + 2) * 4);
  float4 b0 = *(const float4*)(Bbase + lq * 4);
  float4 b1 = *(const float4*)(Bbase + (lq + 2) * 4);
  {
    const int k0a = lq * 4, k0b = (lq + 2) * 4;
    As[0][k0a + 0][lrow] = a0.x; As[0][k0a + 1][lrow] = a0.y;
    As[0][k0a + 2][lrow] = a0.z; As[0][k0a + 3][lrow] = a0.w;
    As[0][k0b + 0][lrow] = a1.x; As[0][k0b + 1][lrow] = a1.y;
    As[0][k0b + 2][lrow] = a1.z; As[0][k0b + 3][lrow] = a1.w;
    Bs[0][k0a + 0][lrow] = b0.x; Bs[0][k0a + 1][lrow] = b0.y;
    Bs[0][k0a + 2][lrow] = b0.z; Bs[0][k0a + 3][lrow] = b0.w;
    Bs[0][k0b + 0][lrow] = b1.x; Bs[0][k0b + 1][lrow] = b1.y;
    Bs[0][k0b + 2][lrow] = b1.z; Bs[0][k0b + 3][lrow] = b1.w;
  }
  __syncthreads();

  for (int ch = 0; ch < 32; ++ch) {
    const int cur = ch & 1, nxt = cur ^ 1;
    if (ch < 31) {
      const int kg = (ch + 1) * 16;
      a0 = *(const float4*)(Abase + kg + lq * 4);
      a1 = *(const float4*)(Abase + kg + (lq + 2) * 4);
      b0 = *(const float4*)(Bbase + kg + lq * 4);
      b1 = *(const float4*)(Bbase + kg + (lq + 2) * 4);
    }
#pragma unroll
    for (int k = 0; k < 16; ++k) {
      const float4 av0 = *(const float4*)&As[cur][k][ty * 4];
      const float4 av1 = *(const float4*)&As[cur][k][64 + ty * 4];
      const float4 bv0 = *(const float4*)&Bs[cur][k][tx * 4];
      const float4 bv1 = *(const float4*)&Bs[cur][k][64 + tx * 4];
      const float a[8] = {av0.x, av0.y, av0.z, av0.w, av1.x, av1.y, av1.z, av1.w};
      const float b[8] = {bv0.x, bv0.y, bv0.z, bv0.w, bv1.x, bv1.y, bv1.z, bv1.w};
#pragma unroll
      for (int m = 0; m < 8; ++m)
#pragma unroll
        for (int n = 0; n < 8; ++n)
          acc[m][n] = __builtin_fmaf(a[m], b[n], acc[m][n]);  // strict k-order chain
    }
    if (ch < 31) {
      const int k0a = lq * 4, k0b = (lq + 2) * 4;
      As[nxt][k0a + 0][lrow] = a0.x; As[nxt][k0a + 1][lrow] = a0.y;
      As[nxt][k0a + 2][lrow] = a0.z; As[nxt][k0a + 3][lrow] = a0.w;
      As[nxt][k0b + 0][lrow] = a1.x; As[nxt][k0b + 1][lrow] = a1.y;
      As[nxt][k0b + 2][lrow] = a1.z; As[nxt][k0b + 3][lrow] = a1.w;
      Bs[nxt][k0a + 0][lrow] = b0.x; Bs[nxt][k0a + 1][lrow] = b0.y;
      Bs[nxt][k0a + 2][lrow] = b0.z; Bs[nxt][k0a + 3][lrow] = b0.w;
      Bs[nxt][k0b + 0][lrow] = b1.x; Bs[nxt][k0b + 1][lrow] = b1.y;
      Bs[nxt][k0b + 2][lrow] = b1.z; Bs[nxt][k0b + 3][lrow] = b1.w;
    }
    __syncthreads();
  }

  // epilogue: /0.07f store + fused per-row max (ordered keys)
  if (t < 128) rmax[t] = 0;
  __syncthreads();
#pragma unroll
  for (int m = 0; m < 8; ++m) {
    const int lrowc = (m < 4) ? (ty * 4 + m) : (64 + ty * 4 + m - 4);
    float v[8];
    unsigned km = 0;
#pragma unroll
    for (int n = 0; n < 8; ++n) {
      v[n] = acc[m][n] / 0.07f;         // IEEE fp32 div (reference-exact)
      const unsigned kk = key_of(v[n]);
      km = kk > km ? kk : km;
    }
    float4 q0 = {v[0], v[1], v[2], v[3]};
    float4 q1 = {v[4], v[5], v[6], v[7]};
    *(float4*)&adc[(size_t)(i0 + lrowc) * Bn + j0 + tx * 4]      = q0;
    *(float4*)&adc[(size_t)(i0 + lrowc) * Bn + j0 + 64 + tx * 4] = q1;
    atomicMax(&rmax[lrowc], km);
  }
  __syncthreads();
  if (t < 128) atomicMax(&rowKey[i0 + t], rmax[t]);
}

// ---------------- histogram pass 1 (linear buckets) ----------------
__global__ __launch_bounds__(256) void hist1_k(const float* __restrict__ adc,
                                               const unsigned* __restrict__ rowKey,
                                               const int* __restrict__ labels,
                                               Ctl* c) {
  __shared__ unsigned h[4096];
  __shared__ int slab[Bn];
  const int t = threadIdx.x;
  for (int q = t; q < 4096; q += 256) h[q] = 0;
  for (int j = t; j < Bn; j += 256) slab[j] = labels[j];
  __syncthreads();
  for (int rr = 0; rr < 8; ++rr) {
    const int i = blockIdx.x * 8 + rr;
    const int li = slab[i];
    const float rm = key_to_float(rowKey[i]);
    for (int j = t; j < Bn; j += 256) {
      if (j == i || slab[j] == li) continue;
      const float L = adc[(size_t)i * Bn + j] - rm;
      atomicAdd(&h[idx1_of(L)], 1u);
    }
  }
  __syncthreads();
  for (int q = t; q < 4096; q += 256)
    if (h[q]) atomicAdd(&c->hist1[q], h[q]);
}

// ---------------- select bucket b1 (n_neg = sum of hist1) ----------------
__global__ __launch_bounds__(256) void select1_k(Ctl* c) {
  __shared__ unsigned tsum[256], suffix[256];
  __shared__ unsigned kk;
  const int t = threadIdx.x;
  unsigned hv[16];
  unsigned s = 0;
#pragma unroll
  for (int u = 0; u < 16; ++u) { hv[u] = c->hist1[t * 16 + u]; s += hv[u]; }
  tsum[t] = s;
  __syncthreads();
  if (t == 0) {
    unsigned tot = 0;
    for (int q = 0; q < 256; ++q) tot += tsum[q];
    unsigned k = tot >> 1;          // floor(0.5 * n_neg), exact vs ref
    if (k < 1) k = 1;
    c->k = k; kk = k;
    unsigned acc = 0;
    for (int q = 255; q >= 0; --q) { suffix[q] = acc; acc += tsum[q]; }
  }
  __syncthreads();
  unsigned cum = suffix[t];
  for (int u = 15; u >= 0; --u) {
    if (cum < kk && cum + hv[u] >= kk) { c->b1 = t * 16 + u; c->above1 = cum; }
    cum += hv[u];
  }
}

// ---------------- histogram pass 2 + candidate collection (fused) ----------------
__global__ __launch_bounds__(256) void hist2c_k(const float* __restrict__ adc,
                                                const unsigned* __restrict__ rowKey,
                                                const int* __restrict__ labels,
                                                Ctl* c) {
  __shared__ unsigned h[4096];
  __shared__ unsigned list[4096];
  __shared__ int slab[Bn];
  __shared__ unsigned lcnt, gbase;
  const int t = threadIdx.x;
  const int b1 = c->b1;
  const float lo1 = -64.0f + (float)b1 * (1.0f / 64.0f);
  for (int q = t; q < 4096; q += 256) h[q] = 0;
  for (int j = t; j < Bn; j += 256) slab[j] = labels[j];
  if (t == 0) lcnt = 0;
  __syncthreads();
  for (int rr = 0; rr < 8; ++rr) {
    const int i = blockIdx.x * 8 + rr;
    const int li = slab[i];
    const float rm = key_to_float(rowKey[i]);
    for (int j = t; j < Bn; j += 256) {
      if (j == i || slab[j] == li) continue;
      const float L = adc[(size_t)i * Bn + j] - rm;
      if (idx1_of(L) == b1) {
        atomicAdd(&h[idx2_of(L, lo1)], 1u);
        unsigned p = atomicAdd(&lcnt, 1u);
        if (p < 4096u) list[p] = key_of(L);
      }
    }
  }
  __syncthreads();
  for (int q = t; q < 4096; q += 256)
    if (h[q]) atomicAdd(&c->hist2[q], h[q]);
  if (t == 0 && lcnt) gbase = atomicAdd(&c->candCount, lcnt < 4096u ? lcnt : 4096u);
  __syncthreads();
  const unsigned nl = lcnt < 4096u ? lcnt : 4096u;
  for (unsigned q = t; q < nl; q += 256) {
    const unsigned p = gbase + q;
    if (p < (unsigned)CAP) c->cand[p] = list[q];
  }
}

// ---------------- select b2 + exact k-th among candidates ----------------
__global__ __launch_bounds__(256) void select2_k(Ctl* c) {
  __shared__ unsigned tsum[256], suffix[256];
  __shared__ int sb2;
  __shared__ unsigned sab2, m;
  __shared__ unsigned list[2048];
  const int t = threadIdx.x;
  const unsigned kk = c->k, base = c->above1;
  unsigned hv[16];
  unsigned s = 0;
#pragma unroll
  for (int u = 0; u < 16; ++u) { hv[u] = c->hist2[t * 16 + u]; s += hv[u]; }
  tsum[t] = s;
  __syncthreads();
  if (t == 0) {
    unsigned acc = base;
    for (int q = 255; q >= 0; --q) { suffix[q] = acc; acc += tsum[q]; }
    m = 0;
  }
  __syncthreads();
  unsigned cum = suffix[t];
  for (int u = 15; u >= 0; --u) {
    if (cum < kk && cum + hv[u] >= kk) { sb2 = t * 16 + u; sab2 = cum; }
    cum += hv[u];
  }
  __syncthreads();
  const int b1 = c->b1;
  const float lo1 = -64.0f + (float)b1 * (1.0f / 64.0f);
  const int b2 = sb2;
  const unsigned r = kk - sab2;    // 1-indexed rank within bucket (b1,b2)
  unsigned n = c->candCount; if (n > (unsigned)CAP) n = (unsigned)CAP;
  for (unsigned q = t; q < n; q += 256) {
    const unsigned key = c->cand[q];
    const float L = key_to_float(key);
    if (idx2_of(L, lo1) == b2) {
      const unsigned p = atomicAdd(&m, 1u);
      if (p < 2048u) list[p] = key;
    }
  }
  __syncthreads();
  const unsigned mm = m > 2048u ? 2048u : m;
  for (unsigned q = t; q < mm; q += 256) {
    const unsigned v = list[q];
    unsigned g = 0, ge = 0;
    for (unsigned j = 0; j < mm; ++j) {
      g  += (list[j] > v);
      ge += (list[j] >= v);
    }
    if (g < r && r <= ge) c->thrF = key_to_float(v);  // duplicates write same value
  }
}

__device__ inline float block_sum_f(float v) {
  __shared__ float s[4];
#pragma unroll
  for (int o = 32; o > 0; o >>= 1) v += __shfl_down(v, o, 64);
  const int lane = threadIdx.x & 63, w = threadIdx.x >> 6;
  __syncthreads();
  if (lane == 0) s[w] = v;
  __syncthreads();
  return s[0] + s[1] + s[2] + s[3];
}

// ---------------- fused mask + loss pass, one block per row ----------------
__global__ __launch_bounds__(256) void final_k(const float* __restrict__ adc,
                                               const unsigned* __restrict__ rowKey,
                                               const int* __restrict__ labels,
                                               Ctl* c, float* __restrict__ out) {
  __shared__ int slab[Bn];
  const int i = blockIdx.x;
  const int t = threadIdx.x;
  for (int j = t; j < Bn; j += 256) slab[j] = labels[j];
  __syncthreads();
  const int li = slab[i];
  const float rm = key_to_float(rowKey[i]);
  const float thr = c->thrF;
  float* __restrict__ ohnm = out + 1;
  float* __restrict__ ofin = out + 1 + (size_t)Bn * Bn;

  float se = 0.0f, sp = 0.0f;
  int pcnt = 0;
#pragma unroll
  for (int e = 0; e < 8; ++e) {
    const int j = t + 256 * e;
    const float L = adc[(size_t)i * Bn + j] - rm;   // identical fp32 value as hist passes
    const bool offd = (j != i);
    const bool same = (slab[j] == li);
    const bool hnm  = offd && !same && (L >= thr);  // exact fp32 compare
    const bool fin  = offd && (same || hnm);
    if (offd) se += __expf(L);
    if (fin)  { sp += L; ++pcnt; }
    ohnm[(size_t)i * Bn + j] = hnm ? 1.0f : 0.0f;
    ofin[(size_t)i * Bn + j] = fin ? 1.0f : 0.0f;
  }
  se = block_sum_f(se);
  sp = block_sum_f(sp);
  float pcf = block_sum_f((float)pcnt);
  if (t == 0) {
    const double P = (double)pcf;
    const bool single = (P == 0.0);
    const double mlpp = ((double)sp - P * log((double)se + 1e-12)) / (P + (single ? 1.0 : 0.0));
    const double lv = single ? 0.0 : -mlpp;
    atomicAdd(&c->lossSum, lv);
    if (single) atomicAdd(&c->singles, 1u);
  }
}

__global__ void finalize_k(const Ctl* c, float* out) {
  out[0] = (float)(c->lossSum / ((double)Bn - (double)c->singles));
}

// ---------------- launch ----------------
extern "C" void kernel_launch(void* const* d_in, const int* in_sizes, int n_in,
                              void* d_out, int out_size, void* d_ws, size_t ws_size,
                              hipStream_t stream) {
  const float* F      = (const float*)d_in[0];
  const int*   labels = (const int*)d_in[1];
  float* out = (float*)d_out;

  char* ws = (char*)d_ws;
  float*    adc    = (float*)ws;                                  // 16.78 MB
  unsigned* rowKey = (unsigned*)(ws + (size_t)Bn * Bn * 4);       // 8 KB
  Ctl*      c      = (Ctl*)(ws + (size_t)Bn * Bn * 4 + (size_t)Bn * 4);

  // zero rowKey + Ctl scalars/hists (cand[] needs no init)
  hipMemsetAsync(rowKey, 0, (size_t)Bn * 4 + offsetof(Ctl, cand), stream);

  gemm_adc<<<dim3(16, 16), 256, 0, stream>>>(F, adc, rowKey);
  hist1_k<<<Bn / 8, 256, 0, stream>>>(adc, rowKey, labels, c);
  select1_k<<<1, 256, 0, stream>>>(c);
  hist2c_k<<<Bn / 8, 256, 0, stream>>>(adc, rowKey, labels, c);
  select2_k<<<1, 256, 0, stream>>>(c);
  final_k<<<Bn, 256, 0, stream>>>(adc, rowKey, labels, c, out);
  finalize_k<<<1, 1, 0, stream>>>(c, out);
}